// Round 6
// baseline (25.012 us; speedup 1.0000x reference)
//
#include <hip/hip_runtime.h>
#include <stdint.h>

#define NV 4096

typedef __attribute__((ext_vector_type(8))) short bf16x8;
typedef __attribute__((ext_vector_type(4))) float f32x4;

__device__ __forceinline__ unsigned short f2bf(float f) {
  union { float f; unsigned int u; } v; v.f = f;
  unsigned int r = v.u + 0x7FFF + ((v.u >> 16) & 1);  // RNE
  return (unsigned short)(r >> 16);
}

// fused prep: blocks 0..1023 convert feature_map f32->bf16 (8 elems/thread);
// blocks 1024..1295 permute weights (64 x 1088, f=c*17+k) -> Wb[k][o][c] bf16.
__global__ __launch_bounds__(256)
void prep(const float* __restrict__ fm, const float* __restrict__ w,
          unsigned short* __restrict__ fmb, unsigned short* __restrict__ wb) {
  int blk = blockIdx.x;
  if (blk < 1024) {
    int i = (blk * 256 + threadIdx.x) * 8;
    float4 v0 = *(const float4*)(fm + i);
    float4 v1 = *(const float4*)(fm + i + 4);
    ushort4 o0, o1;
    o0.x = f2bf(v0.x); o0.y = f2bf(v0.y); o0.z = f2bf(v0.z); o0.w = f2bf(v0.w);
    o1.x = f2bf(v1.x); o1.y = f2bf(v1.y); o1.z = f2bf(v1.z); o1.w = f2bf(v1.w);
    *(ushort4*)(fmb + i) = o0;
    *(ushort4*)(fmb + i + 4) = o1;
  } else {
    int t = (blk - 1024) * 256 + threadIdx.x;  // 0..69631 (= 17*64*64)
    int c = t & 63;
    int o = (t >> 6) & 63;
    int k = t >> 12;
    wb[t] = f2bf(w[o * 1088 + c * 17 + k]);
  }
}

// Gather-GEMM, swapped-operand form (out tile = W_tile x F_tile^T):
//  - W fully LDS-resident (139KB staged once, pre-swizzled source).
//  - F gathered straight to VGPR; ALL of a wave's slots issued upfront.
//  - Raw barrier with counted vmcnt: staging drained, F stays in flight.
//  - Epilogue: lane holds 4 consecutive channels -> f32x4 stores.
// Block = 512 thr = 8 waves = 4 row-groups x 2 K-halves; 128 rows/block.
__global__ __launch_bounds__(512, 2)
void conv_main(const int* __restrict__ nbr, const unsigned short* __restrict__ fmb,
               const unsigned short* __restrict__ wb, const float* __restrict__ bias,
               float* __restrict__ out) {
  __shared__ unsigned short smem[17 * 4096];  // 139264 B

  const int bid = blockIdx.x;
  const int b = bid & 7;                // batch == XCD
  const int tile = bid >> 3;            // 0..31
  const int tid = threadIdx.x;
  const int lane = tid & 63;
  const int lm = lane & 15;
  const int lk = lane >> 4;
  const int w8 = tid >> 6;              // wave 0..7
  const int rg = w8 >> 1;               // row-group 0..3 (32 rows each)
  const int h = w8 & 1;                 // K-half

  const int rbase = tile * 128 + rg * 32;
  const int row0 = rbase + lm;
  const int row1 = rbase + 16 + lm;

  const bf16x8* fb = (const bf16x8*)(fmb + (size_t)b * NV * 64);

  // (1) neighbor indices for this K-half (8 per row)
  const int4* q0 = (const int4*)(nbr + ((size_t)b * NV + row0) * 16) + h * 2;
  const int4* q1 = (const int4*)(nbr + ((size_t)b * NV + row1) * 16) + h * 2;
  const int4 i0a = q0[0], i0b = q0[1];
  const int4 i1a = q1[0], i1b = q1[1];

  // (2) stage all 17 weight slots into LDS, source pre-swizzled (rule #21)
  #pragma unroll
  for (int i = 0; i < 17; ++i) {
    int t = i * 512 + tid;
    int slot = t >> 9;
    int r = (t >> 3) & 63;
    int sl = t & 7;
    int seg = sl ^ (r & 7);
    const unsigned short* src = wb + (size_t)slot * 4096 + r * 64 + seg * 8;
    unsigned short* dst = smem + (size_t)t * 8;
    __builtin_amdgcn_global_load_lds(
        (const __attribute__((address_space(1))) void*)src,
        (__attribute__((address_space(3))) void*)dst, 16, 0, 0);
  }
  __builtin_amdgcn_sched_barrier(0);   // pin: all staging issued before F loads

  // (3) F prefetch: all slots of this wave's K-half, named regs (rule #20)
  bf16x8 F0m0h0, F0m0h1, F0m1h0, F0m1h1;
  bf16x8 F1m0h0, F1m0h1, F1m1h0, F1m1h1;
  bf16x8 F2m0h0, F2m0h1, F2m1h0, F2m1h1;
  bf16x8 F3m0h0, F3m0h1, F3m1h0, F3m1h1;
  bf16x8 F4m0h0, F4m0h1, F4m1h0, F4m1h1;
  bf16x8 F5m0h0, F5m0h1, F5m1h0, F5m1h1;
  bf16x8 F6m0h0, F6m0h1, F6m1h0, F6m1h1;
  bf16x8 F7m0h0, F7m0h1, F7m1h0, F7m1h1;
  bf16x8 F8m0h0, F8m0h1, F8m1h0, F8m1h1;

#define LOADF(J, SV0, SV1) {                          \
    const bf16x8* p0_ = fb + (size_t)(SV0) * 8;       \
    const bf16x8* p1_ = fb + (size_t)(SV1) * 8;       \
    F##J##m0h0 = p0_[lk];  F##J##m0h1 = p0_[lk + 4];  \
    F##J##m1h0 = p1_[lk];  F##J##m1h1 = p1_[lk + 4];  \
  }

  if (h == 0) {
    LOADF(0, row0, row1);                               // self (coalesced)
    LOADF(1, i0a.x, i1a.x); LOADF(2, i0a.y, i1a.y);
    LOADF(3, i0a.z, i1a.z); LOADF(4, i0a.w, i1a.w);
    LOADF(5, i0b.x, i1b.x); LOADF(6, i0b.y, i1b.y);
    LOADF(7, i0b.z, i1b.z); LOADF(8, i0b.w, i1b.w);
  } else {
    LOADF(0, i0a.x, i1a.x); LOADF(1, i0a.y, i1a.y);
    LOADF(2, i0a.z, i1a.z); LOADF(3, i0a.w, i1a.w);
    LOADF(4, i0b.x, i1b.x); LOADF(5, i0b.y, i1b.y);
    LOADF(6, i0b.z, i1b.z); LOADF(7, i0b.w, i1b.w);
  }

  // (4) barrier with counted vmcnt: staging (issued before F) is complete
  //     once outstanding <= #F-loads; F gathers stay in flight.
  __builtin_amdgcn_sched_barrier(0);
  if (h == 0) { asm volatile("s_waitcnt vmcnt(36)" ::: "memory"); }
  else        { asm volatile("s_waitcnt vmcnt(32)" ::: "memory"); }
  __builtin_amdgcn_sched_barrier(0);
  __builtin_amdgcn_s_barrier();
  __builtin_amdgcn_sched_barrier(0);

  // swizzled LDS read offsets (identical to R5's verified B-read pattern)
  const int off0 = lm * 128 + ((lk ^ (lm & 7)) << 4);
  const int off1 = off0 ^ 64;

  f32x4 acc00{0,0,0,0}, acc01{0,0,0,0}, acc02{0,0,0,0}, acc03{0,0,0,0};
  f32x4 acc10{0,0,0,0}, acc11{0,0,0,0}, acc12{0,0,0,0}, acc13{0,0,0,0};

#define MFMA __builtin_amdgcn_mfma_f32_16x16x32_bf16
#define PHASE(J, SLOT) {                                            \
    const char* bp_ = ((const char*)smem) + (SLOT) * 8192;          \
    bf16x8 W0a = *(const bf16x8*)(bp_ + 0 * 2048 + off0);           \
    bf16x8 W0b = *(const bf16x8*)(bp_ + 0 * 2048 + off1);           \
    bf16x8 W1a = *(const bf16x8*)(bp_ + 1 * 2048 + off0);           \
    bf16x8 W1b = *(const bf16x8*)(bp_ + 1 * 2048 + off1);           \
    bf16x8 W2a = *(const bf16x8*)(bp_ + 2 * 2048 + off0);           \
    bf16x8 W2b = *(const bf16x8*)(bp_ + 2 * 2048 + off1);           \
    bf16x8 W3a = *(const bf16x8*)(bp_ + 3 * 2048 + off0);           \
    bf16x8 W3b = *(const bf16x8*)(bp_ + 3 * 2048 + off1);           \
    acc00 = MFMA(W0a, F##J##m0h0, acc00, 0, 0, 0);                  \
    acc00 = MFMA(W0b, F##J##m0h1, acc00, 0, 0, 0);                  \
    acc10 = MFMA(W0a, F##J##m1h0, acc10, 0, 0, 0);                  \
    acc10 = MFMA(W0b, F##J##m1h1, acc10, 0, 0, 0);                  \
    acc01 = MFMA(W1a, F##J##m0h0, acc01, 0, 0, 0);                  \
    acc01 = MFMA(W1b, F##J##m0h1, acc01, 0, 0, 0);                  \
    acc11 = MFMA(W1a, F##J##m1h0, acc11, 0, 0, 0);                  \
    acc11 = MFMA(W1b, F##J##m1h1, acc11, 0, 0, 0);                  \
    acc02 = MFMA(W2a, F##J##m0h0, acc02, 0, 0, 0);                  \
    acc02 = MFMA(W2b, F##J##m0h1, acc02, 0, 0, 0);                  \
    acc12 = MFMA(W2a, F##J##m1h0, acc12, 0, 0, 0);                  \
    acc12 = MFMA(W2b, F##J##m1h1, acc12, 0, 0, 0);                  \
    acc03 = MFMA(W3a, F##J##m0h0, acc03, 0, 0, 0);                  \
    acc03 = MFMA(W3b, F##J##m0h1, acc03, 0, 0, 0);                  \
    acc13 = MFMA(W3a, F##J##m1h0, acc13, 0, 0, 0);                  \
    acc13 = MFMA(W3b, F##J##m1h1, acc13, 0, 0, 0);                  \
  }

  if (h == 0) {
    PHASE(0, 0); PHASE(1, 1); PHASE(2, 2); PHASE(3, 3); PHASE(4, 4);
    PHASE(5, 5); PHASE(6, 6); PHASE(7, 7); PHASE(8, 8);
  } else {
    PHASE(0, 9); PHASE(1, 10); PHASE(2, 11); PHASE(3, 12);
    PHASE(4, 13); PHASE(5, 14); PHASE(6, 15); PHASE(7, 16);
  }

#undef PHASE
#undef MFMA
#undef LOADF

  // ---- combine K-halves through LDS (reuses dead W region), then epilogue
  __syncthreads();
  if (h == 1) {
    float* rp = (float*)smem + rg * 2048 + lane * 4;
    *(f32x4*)(rp + 0 * 256) = acc00;
    *(f32x4*)(rp + 1 * 256) = acc01;
    *(f32x4*)(rp + 2 * 256) = acc02;
    *(f32x4*)(rp + 3 * 256) = acc03;
    *(f32x4*)(rp + 4 * 256) = acc10;
    *(f32x4*)(rp + 5 * 256) = acc11;
    *(f32x4*)(rp + 6 * 256) = acc12;
    *(f32x4*)(rp + 7 * 256) = acc13;
  }
  __syncthreads();
  if (h == 0) {
    const float* rp = (const float*)smem + rg * 2048 + lane * 4;
    acc00 += *(const f32x4*)(rp + 0 * 256);
    acc01 += *(const f32x4*)(rp + 1 * 256);
    acc02 += *(const f32x4*)(rp + 2 * 256);
    acc03 += *(const f32x4*)(rp + 3 * 256);
    acc10 += *(const f32x4*)(rp + 4 * 256);
    acc11 += *(const f32x4*)(rp + 5 * 256);
    acc12 += *(const f32x4*)(rp + 6 * 256);
    acc13 += *(const f32x4*)(rp + 7 * 256);

    // bias for this lane's 4 consecutive channels per n-tile
    const f32x4 bv0 = *(const f32x4*)(bias + 0  + lk * 4);
    const f32x4 bv1 = *(const f32x4*)(bias + 16 + lk * 4);
    const f32x4 bv2 = *(const f32x4*)(bias + 32 + lk * 4);
    const f32x4 bv3 = *(const f32x4*)(bias + 48 + lk * 4);
    float* op = out + (size_t)b * NV * 64;

#define STORE1(ACC, BV, V, N) {                                   \
    f32x4 t_ = ACC + BV;                                          \
    t_[0] = fmaxf(t_[0], 0.f); t_[1] = fmaxf(t_[1], 0.f);         \
    t_[2] = fmaxf(t_[2], 0.f); t_[3] = fmaxf(t_[3], 0.f);         \
    *(f32x4*)(op + (size_t)(V) * 64 + (N) * 16 + lk * 4) = t_;    \
  }
    const int v0 = rbase + lm;
    const int v1 = rbase + 16 + lm;
    STORE1(acc00, bv0, v0, 0); STORE1(acc01, bv1, v0, 1);
    STORE1(acc02, bv2, v0, 2); STORE1(acc03, bv3, v0, 3);
    STORE1(acc10, bv0, v1, 0); STORE1(acc11, bv1, v1, 1);
    STORE1(acc12, bv2, v1, 2); STORE1(acc13, bv3, v1, 3);
#undef STORE1
  }
}

extern "C" void kernel_launch(void* const* d_in, const int* in_sizes, int n_in,
                              void* d_out, int out_size, void* d_ws, size_t ws_size,
                              hipStream_t stream) {
  const int* nbr = (const int*)d_in[0];
  // d_in[1] = vertices (unused by the reference computation)
  const float* fm = (const float*)d_in[2];
  const float* w = (const float*)d_in[3];
  const float* bias = (const float*)d_in[4];
  float* out = (float*)d_out;

  unsigned short* fmb = (unsigned short*)d_ws;          // 8*4096*64 bf16 = 4 MB
  unsigned short* wb = fmb + (size_t)8 * NV * 64;       // 17*64*64 bf16

  prep<<<1296, 256, 0, stream>>>(fm, w, fmb, wb);
  conv_main<<<256, 512, 0, stream>>>(nbr, fmb, wb, bias, out);
}

// Round 7
// 24.792 us; speedup vs baseline: 1.0089x; 1.0089x over previous
//
#include <hip/hip_runtime.h>
#include <stdint.h>

#define NV 4096
#define WSLOT 69632   // 17*64*64 bf16 elements per weight copy

typedef __attribute__((ext_vector_type(8))) short bf16x8;
typedef __attribute__((ext_vector_type(4))) float f32x4;

__device__ __forceinline__ unsigned short f2bf(float f) {
  union { float f; unsigned int u; } v; v.f = f;
  unsigned int r = v.u + 0x7FFF + ((v.u >> 16) & 1);  // RNE
  return (unsigned short)(r >> 16);
}

// prep with XCD affinity (block&7 == consuming XCD):
//  blocks 0..1023: fm f32->bf16; block j owns batch (j&7), chunk (j>>3).
//  blocks 1024..3199: weight permute into 8 per-XCD replicas; copy (j&7).
__global__ __launch_bounds__(256)
void prep(const float* __restrict__ fm, const float* __restrict__ w,
          unsigned short* __restrict__ fmb, unsigned short* __restrict__ wb) {
  int blk = blockIdx.x;
  if (blk < 1024) {
    int b = blk & 7;
    int inner = blk >> 3;              // 0..127
    size_t i = (size_t)b * 262144 + (size_t)inner * 2048 + threadIdx.x * 8;
    float4 v0 = *(const float4*)(fm + i);
    float4 v1 = *(const float4*)(fm + i + 4);
    ushort4 o0, o1;
    o0.x = f2bf(v0.x); o0.y = f2bf(v0.y); o0.z = f2bf(v0.z); o0.w = f2bf(v0.w);
    o1.x = f2bf(v1.x); o1.y = f2bf(v1.y); o1.z = f2bf(v1.z); o1.w = f2bf(v1.w);
    *(ushort4*)(fmb + i) = o0;
    *(ushort4*)(fmb + i + 4) = o1;
  } else {
    int j = blk - 1024;                // 0..2175
    int copy = j & 7;
    int t = (j >> 3) * 256 + threadIdx.x;  // 0..69631
    int c = t & 63;
    int o = (t >> 6) & 63;
    int k = t >> 12;
    wb[(size_t)copy * WSLOT + t] = f2bf(w[o * 1088 + c * 17 + k]);
  }
}

// Gather-GEMM, swapped operands (out tile = W x F^T), CHANNEL-split:
//  - per-XCD weight replica staged to LDS (139KB) once, pre-swizzled source;
//  - wave h consumes channel-half h of all 17 slots -> 1x64B line per gather,
//    all gathers local-XCD-L2 hits (prep affinity);
//  - all 34 F gathers issued upfront; counted vmcnt barrier (staging drained,
//    gathers stay in flight);
//  - h-pair partials combined through LDS; f32x4 epilogue stores.
// Block = 512 thr = 8 waves = 4 row-groups x 2 channel-halves; 128 rows/block.
__global__ __launch_bounds__(512, 2)
void conv_main(const int* __restrict__ nbr, const unsigned short* __restrict__ fmb,
               const unsigned short* __restrict__ wb, const float* __restrict__ bias,
               float* __restrict__ out) {
  __shared__ unsigned short smem[17 * 4096];  // 139264 B

  const int bid = blockIdx.x;
  const int b = bid & 7;                // batch == XCD
  const int tile = bid >> 3;            // 0..31
  const int tid = threadIdx.x;
  const int lane = tid & 63;
  const int lm = lane & 15;
  const int lk = lane >> 4;
  const int w8 = tid >> 6;              // wave 0..7
  const int rg = w8 >> 1;               // row-group 0..3 (32 rows each)
  const int h = w8 & 1;                 // channel half

  const int rbase = tile * 128 + rg * 32;
  const int row0 = rbase + lm;
  const int row1 = rbase + 16 + lm;

  const bf16x8* fb = (const bf16x8*)(fmb + (size_t)b * NV * 64);
  const unsigned short* wbl = wb + (size_t)b * WSLOT;   // local-XCD replica
  const int sl = lk | (h << 2);        // this lane's 16B segment (fixed)

  // (1) all 16 neighbor indices per owned row (issued first, drain under staging)
  const int4* q0 = (const int4*)(nbr + ((size_t)b * NV + row0) * 16);
  const int4* q1 = (const int4*)(nbr + ((size_t)b * NV + row1) * 16);
  const int4 i0a = q0[0], i0b = q0[1], i0c = q0[2], i0d = q0[3];
  const int4 i1a = q1[0], i1b = q1[1], i1c = q1[2], i1d = q1[3];

  // (2) stage all 17 weight slots into LDS from the LOCAL replica,
  //     source pre-swizzled (rule #21)
  #pragma unroll
  for (int i = 0; i < 17; ++i) {
    int t = i * 512 + tid;
    int slot = t >> 9;
    int r = (t >> 3) & 63;
    int s8 = t & 7;
    int seg = s8 ^ (r & 7);
    const unsigned short* src = wbl + (size_t)slot * 4096 + r * 64 + seg * 8;
    unsigned short* dst = smem + (size_t)t * 8;
    __builtin_amdgcn_global_load_lds(
        (const __attribute__((address_space(1))) void*)src,
        (__attribute__((address_space(3))) void*)dst, 16, 0, 0);
  }
  __builtin_amdgcn_sched_barrier(0);   // staging issued before F gathers

  // (3) F gathers: one 16B load per slot per row = 34, all upfront
  bf16x8 F0m0, F0m1, F1m0, F1m1, F2m0, F2m1, F3m0, F3m1, F4m0, F4m1;
  bf16x8 F5m0, F5m1, F6m0, F6m1, F7m0, F7m1, F8m0, F8m1, F9m0, F9m1;
  bf16x8 F10m0, F10m1, F11m0, F11m1, F12m0, F12m1, F13m0, F13m1;
  bf16x8 F14m0, F14m1, F15m0, F15m1, F16m0, F16m1;

#define LOADF(J, SV0, SV1) {                          \
    F##J##m0 = (fb + (size_t)(SV0) * 8)[sl];          \
    F##J##m1 = (fb + (size_t)(SV1) * 8)[sl];          \
  }
  LOADF(0, row0, row1);
  LOADF(1, i0a.x, i1a.x);  LOADF(2, i0a.y, i1a.y);
  LOADF(3, i0a.z, i1a.z);  LOADF(4, i0a.w, i1a.w);
  LOADF(5, i0b.x, i1b.x);  LOADF(6, i0b.y, i1b.y);
  LOADF(7, i0b.z, i1b.z);  LOADF(8, i0b.w, i1b.w);
  LOADF(9, i0c.x, i1c.x);  LOADF(10, i0c.y, i1c.y);
  LOADF(11, i0c.z, i1c.z); LOADF(12, i0c.w, i1c.w);
  LOADF(13, i0d.x, i1d.x); LOADF(14, i0d.y, i1d.y);
  LOADF(15, i0d.z, i1d.z); LOADF(16, i0d.w, i1d.w);
#undef LOADF

  // (4) counted-vmcnt barrier: 34 F loads outstanding => staging complete
  __builtin_amdgcn_sched_barrier(0);
  asm volatile("s_waitcnt vmcnt(34)" ::: "memory");
  __builtin_amdgcn_sched_barrier(0);
  __builtin_amdgcn_s_barrier();
  __builtin_amdgcn_sched_barrier(0);

  // swizzled LDS read offset for this lane's fixed segment
  const int offW = lm * 128 + ((sl ^ (lm & 7)) << 4);

  f32x4 acc00{0,0,0,0}, acc01{0,0,0,0}, acc02{0,0,0,0}, acc03{0,0,0,0};
  f32x4 acc10{0,0,0,0}, acc11{0,0,0,0}, acc12{0,0,0,0}, acc13{0,0,0,0};

#define MFMA __builtin_amdgcn_mfma_f32_16x16x32_bf16
#define PHASE(K) {                                             \
    const char* bp_ = ((const char*)smem) + (K) * 8192;        \
    bf16x8 W0 = *(const bf16x8*)(bp_ + 0 * 2048 + offW);       \
    bf16x8 W1 = *(const bf16x8*)(bp_ + 1 * 2048 + offW);       \
    bf16x8 W2 = *(const bf16x8*)(bp_ + 2 * 2048 + offW);       \
    bf16x8 W3 = *(const bf16x8*)(bp_ + 3 * 2048 + offW);       \
    acc00 = MFMA(W0, F##K##m0, acc00, 0, 0, 0);                \
    acc10 = MFMA(W0, F##K##m1, acc10, 0, 0, 0);                \
    acc01 = MFMA(W1, F##K##m0, acc01, 0, 0, 0);                \
    acc11 = MFMA(W1, F##K##m1, acc11, 0, 0, 0);                \
    acc02 = MFMA(W2, F##K##m0, acc02, 0, 0, 0);                \
    acc12 = MFMA(W2, F##K##m1, acc12, 0, 0, 0);                \
    acc03 = MFMA(W3, F##K##m0, acc03, 0, 0, 0);                \
    acc13 = MFMA(W3, F##K##m1, acc13, 0, 0, 0);                \
  }
  PHASE(0);  PHASE(1);  PHASE(2);  PHASE(3);  PHASE(4);  PHASE(5);
  PHASE(6);  PHASE(7);  PHASE(8);  PHASE(9);  PHASE(10); PHASE(11);
  PHASE(12); PHASE(13); PHASE(14); PHASE(15); PHASE(16);
#undef PHASE
#undef MFMA

  // combine channel halves through LDS (dead W region), then epilogue
  __syncthreads();
  if (h == 1) {
    float* rp = (float*)smem + rg * 2048 + lane * 4;
    *(f32x4*)(rp + 0 * 256) = acc00;
    *(f32x4*)(rp + 1 * 256) = acc01;
    *(f32x4*)(rp + 2 * 256) = acc02;
    *(f32x4*)(rp + 3 * 256) = acc03;
    *(f32x4*)(rp + 4 * 256) = acc10;
    *(f32x4*)(rp + 5 * 256) = acc11;
    *(f32x4*)(rp + 6 * 256) = acc12;
    *(f32x4*)(rp + 7 * 256) = acc13;
  }
  __syncthreads();
  if (h == 0) {
    const float* rp = (const float*)smem + rg * 2048 + lane * 4;
    acc00 += *(const f32x4*)(rp + 0 * 256);
    acc01 += *(const f32x4*)(rp + 1 * 256);
    acc02 += *(const f32x4*)(rp + 2 * 256);
    acc03 += *(const f32x4*)(rp + 3 * 256);
    acc10 += *(const f32x4*)(rp + 4 * 256);
    acc11 += *(const f32x4*)(rp + 5 * 256);
    acc12 += *(const f32x4*)(rp + 6 * 256);
    acc13 += *(const f32x4*)(rp + 7 * 256);

    const f32x4 bv0 = *(const f32x4*)(bias + 0  + lk * 4);
    const f32x4 bv1 = *(const f32x4*)(bias + 16 + lk * 4);
    const f32x4 bv2 = *(const f32x4*)(bias + 32 + lk * 4);
    const f32x4 bv3 = *(const f32x4*)(bias + 48 + lk * 4);
    float* op = out + (size_t)b * NV * 64;

#define STORE1(ACC, BV, V, N) {                                   \
    f32x4 t_ = ACC + BV;                                          \
    t_[0] = fmaxf(t_[0], 0.f); t_[1] = fmaxf(t_[1], 0.f);         \
    t_[2] = fmaxf(t_[2], 0.f); t_[3] = fmaxf(t_[3], 0.f);         \
    *(f32x4*)(op + (size_t)(V) * 64 + (N) * 16 + lk * 4) = t_;    \
  }
    const int v0 = rbase + lm;
    const int v1 = rbase + 16 + lm;
    STORE1(acc00, bv0, v0, 0); STORE1(acc01, bv1, v0, 1);
    STORE1(acc02, bv2, v0, 2); STORE1(acc03, bv3, v0, 3);
    STORE1(acc10, bv0, v1, 0); STORE1(acc11, bv1, v1, 1);
    STORE1(acc12, bv2, v1, 2); STORE1(acc13, bv3, v1, 3);
#undef STORE1
  }
}

extern "C" void kernel_launch(void* const* d_in, const int* in_sizes, int n_in,
                              void* d_out, int out_size, void* d_ws, size_t ws_size,
                              hipStream_t stream) {
  const int* nbr = (const int*)d_in[0];
  // d_in[1] = vertices (unused by the reference computation)
  const float* fm = (const float*)d_in[2];
  const float* w = (const float*)d_in[3];
  const float* bias = (const float*)d_in[4];
  float* out = (float*)d_out;

  unsigned short* fmb = (unsigned short*)d_ws;          // 8*4096*64 bf16 = 4 MB
  unsigned short* wb = fmb + (size_t)8 * NV * 64;       // 8 replicas x 139 KB

  prep<<<3200, 256, 0, stream>>>(fm, w, fmb, wb);
  conv_main<<<256, 512, 0, stream>>>(nbr, fmb, wb, bias, out);
}